// Round 1
// baseline (127.318 us; speedup 1.0000x reference)
//
#include <hip/hip_runtime.h>
#include <math.h>

// ---------------------------------------------------------------------------
// Problem: Att_cov — edge attention (sigmoid linear on [x_row, x_col]) +
// GCNConv(D,1) with self-loops & symmetric norm + per-graph segment softmax.
// Sizes: N=50000 nodes, E=800000 edges, D=64, G=500 graphs.
// Outputs (flat, f32): edge_att_m[E], edge_att_s[E], node_att_m[N], node_att_s[N]
// Workspace: h[N], dinv(deg)[N], acc[N]  (3*N floats = 600 KB)
// ---------------------------------------------------------------------------

__global__ void k_node_init(const float* __restrict__ x,
                            const float* __restrict__ W_gcn,
                            float* __restrict__ h,
                            float* __restrict__ deg,
                            float* __restrict__ acc,
                            int n) {
    __shared__ float Wg[64];
    int tid = threadIdx.x;
    if (tid < 64) Wg[tid] = W_gcn[tid];
    __syncthreads();
    int i = blockIdx.x * blockDim.x + tid;
    if (i < n) {
        const float4* xp = (const float4*)(x + (size_t)i * 64);
        float s = 0.f;
#pragma unroll
        for (int q = 0; q < 16; ++q) {
            float4 v = xp[q];
            s += v.x * Wg[q * 4 + 0] + v.y * Wg[q * 4 + 1] +
                 v.z * Wg[q * 4 + 2] + v.w * Wg[q * 4 + 3];
        }
        h[i] = s;
        deg[i] = 1.0f;   // self-loop
        acc[i] = 0.0f;
    }
}

__global__ void k_deg(const int* __restrict__ col, float* __restrict__ deg, int E) {
    int i = blockIdx.x * blockDim.x + threadIdx.x;
    if (i < E) atomicAdd(&deg[col[i]], 1.0f);
}

__global__ void k_dinv(float* __restrict__ deg_to_dinv,
                       const float* __restrict__ h,
                       float* __restrict__ acc, int n) {
    int i = blockIdx.x * blockDim.x + threadIdx.x;
    if (i < n) {
        float dv = rsqrtf(deg_to_dinv[i]);
        deg_to_dinv[i] = dv;          // buffer now holds dinv
        acc[i] = dv * dv * h[i];      // self-loop contribution to GCN sum
    }
}

// 16 lanes cooperate per edge: lane t loads float4 #t of x[row] and x[col]
// (fully coalesced 256B segments), partial dot with W_edge, shfl-reduce.
__global__ void k_edge(const float* __restrict__ x,
                       const int* __restrict__ ei,      // [2*E]: row then col
                       const float* __restrict__ W_edge, // [128]
                       const float* __restrict__ b_edge, // [1]
                       const float* __restrict__ h,
                       const float* __restrict__ dinv,
                       float* __restrict__ acc,
                       float* __restrict__ out_m,
                       float* __restrict__ out_s,
                       int E) {
    __shared__ float We[128];
    int tid = threadIdx.x;
    if (tid < 128) We[tid] = W_edge[tid];
    __syncthreads();
    int lane = tid & 15;
    long long gid = (long long)blockIdx.x * blockDim.x + tid;
    int e = (int)(gid >> 4);
    if (e >= E) return;
    int row = ei[e];
    int col = ei[E + e];
    const float4* xr = (const float4*)(x + (size_t)row * 64);
    const float4* xc = (const float4*)(x + (size_t)col * 64);
    float4 a = xr[lane];
    float4 b = xc[lane];
    const float4* W4 = (const float4*)We;
    float4 wa = W4[lane];
    float4 wb = W4[16 + lane];
    float p = a.x * wa.x + a.y * wa.y + a.z * wa.z + a.w * wa.w +
              b.x * wb.x + b.y * wb.y + b.z * wb.z + b.w * wb.w;
    p += __shfl_xor(p, 1);
    p += __shfl_xor(p, 2);
    p += __shfl_xor(p, 4);
    p += __shfl_xor(p, 8);
    if (lane == 0) {
        float att = 1.0f / (1.0f + expf(-(p + b_edge[0])));
        out_m[e] = att;
        out_s[e] = 1.0f - att;
        atomicAdd(&acc[col], dinv[row] * dinv[col] * h[row]);
    }
}

// One block per graph. Two chained segment softmaxes.
__global__ void k_softmax(const float* __restrict__ acc,
                          const float* __restrict__ b_gcn,
                          const int* __restrict__ split_n,
                          float* __restrict__ out_m,
                          float* __restrict__ out_s) {
    __shared__ float red[128];
    __shared__ int ired[128];
    __shared__ int sh_off;
    const int g = blockIdx.x;
    const int tid = threadIdx.x;
    const int BD = blockDim.x; // 128

    // offset = prefix sum of split_n[0..g)
    int part = 0;
    for (int j = tid; j < g; j += BD) part += split_n[j];
    ired[tid] = part;
    __syncthreads();
    for (int s = 64; s > 0; s >>= 1) {
        if (tid < s) ired[tid] += ired[tid + s];
        __syncthreads();
    }
    if (tid == 0) sh_off = ired[0];
    __syncthreads();
    const int off = sh_off;
    const int cnt = split_n[g];
    const float b = b_gcn[0];

    // ---- softmax #1 over (acc + b) ----
    float mx = -INFINITY;
    for (int j = tid; j < cnt; j += BD) mx = fmaxf(mx, acc[off + j] + b);
    red[tid] = mx; __syncthreads();
    for (int s = 64; s > 0; s >>= 1) {
        if (tid < s) red[tid] = fmaxf(red[tid], red[tid + s]);
        __syncthreads();
    }
    mx = red[0]; __syncthreads();
    float sum = 0.f;
    for (int j = tid; j < cnt; j += BD) sum += expf(acc[off + j] + b - mx);
    red[tid] = sum; __syncthreads();
    for (int s = 64; s > 0; s >>= 1) {
        if (tid < s) red[tid] += red[tid + s];
        __syncthreads();
    }
    const float inv1 = 1.0f / red[0]; __syncthreads();
    for (int j = tid; j < cnt; j += BD)
        out_m[off + j] = expf(acc[off + j] + b - mx) * inv1;
    __syncthreads();  // block-level fence: out_m visible to this block

    // ---- softmax #2 over (1 - out_m) ----
    float mx2 = -INFINITY;
    for (int j = tid; j < cnt; j += BD) mx2 = fmaxf(mx2, 1.0f - out_m[off + j]);
    red[tid] = mx2; __syncthreads();
    for (int s = 64; s > 0; s >>= 1) {
        if (tid < s) red[tid] = fmaxf(red[tid], red[tid + s]);
        __syncthreads();
    }
    mx2 = red[0]; __syncthreads();
    float sum2 = 0.f;
    for (int j = tid; j < cnt; j += BD) sum2 += expf(1.0f - out_m[off + j] - mx2);
    red[tid] = sum2; __syncthreads();
    for (int s = 64; s > 0; s >>= 1) {
        if (tid < s) red[tid] += red[tid + s];
        __syncthreads();
    }
    const float inv2 = 1.0f / red[0]; __syncthreads();
    for (int j = tid; j < cnt; j += BD)
        out_s[off + j] = expf(1.0f - out_m[off + j] - mx2) * inv2;
}

extern "C" void kernel_launch(void* const* d_in, const int* in_sizes, int n_in,
                              void* d_out, int out_size, void* d_ws, size_t ws_size,
                              hipStream_t stream) {
    const float* x      = (const float*)d_in[0];
    const int*   ei     = (const int*)d_in[1];
    const int*   splitn = (const int*)d_in[2];
    const float* W_edge = (const float*)d_in[3];
    const float* b_edge = (const float*)d_in[4];
    const float* W_gcn  = (const float*)d_in[5];
    const float* b_gcn  = (const float*)d_in[6];

    const int N = in_sizes[0] / 64;
    const int E = in_sizes[1] / 2;
    const int G = in_sizes[2];

    float* out = (float*)d_out;
    float* edge_m = out;
    float* edge_s = out + E;
    float* node_m = out + 2LL * E;
    float* node_s = out + 2LL * E + N;

    float* ws  = (float*)d_ws;
    float* h    = ws;
    float* dinv = ws + N;       // holds deg first, then dinv
    float* acc  = ws + 2LL * N;

    k_node_init<<<(N + 255) / 256, 256, 0, stream>>>(x, W_gcn, h, dinv, acc, N);
    k_deg<<<(E + 255) / 256, 256, 0, stream>>>(ei + E, dinv, E);
    k_dinv<<<(N + 255) / 256, 256, 0, stream>>>(dinv, h, acc, N);
    const long long tot = 16LL * E;
    k_edge<<<(int)((tot + 255) / 256), 256, 0, stream>>>(
        x, ei, W_edge, b_edge, h, dinv, acc, edge_m, edge_s, E);
    k_softmax<<<G, 128, 0, stream>>>(acc, b_gcn, splitn, node_m, node_s);
}

// Round 2
// 118.930 us; speedup vs baseline: 1.0705x; 1.0705x over previous
//
#include <hip/hip_runtime.h>
#include <math.h>

// ---------------------------------------------------------------------------
// Att_cov: edge attention sigmoid(x[row]·Wa + x[col]·Wb + b) + GCNConv(D,1)
// with self-loops & symmetric norm + per-graph segment softmax.
// Key idea: the 2D-wide edge linear is separable -> precompute per-node
// scalars pa=x·Wa, pb=x·Wb, h=x·Wgcn once (x read ONCE), pack
// (pa, pb, g=dinv*h, dinv) into float4[N] (800KB, L2-resident) so the edge
// pass gathers 16B/endpoint instead of 256B.
// ws layout: nd float4[N] | dacc float[N] (deg -> acc)   = 20N bytes (1 MB)
// ---------------------------------------------------------------------------

// Fused: blocks [0, nodeBlocks) do the per-node projections (16 lanes/node,
// coalesced float4 reads of x); blocks [nodeBlocks, ...) do degree atomics.
__global__ void k_node_deg(const float* __restrict__ x,
                           const float* __restrict__ W_edge,
                           const float* __restrict__ W_gcn,
                           const int* __restrict__ colv,
                           float4* __restrict__ nd,
                           float* __restrict__ dacc,
                           int N, int E, int nodeBlocks) {
    if ((int)blockIdx.x < nodeBlocks) {
        __shared__ float4 Wa[16], Wb[16], Wg[16];
        int tid = threadIdx.x;
        if (tid < 16) {
            Wa[tid] = ((const float4*)W_edge)[tid];
            Wb[tid] = ((const float4*)W_edge)[16 + tid];
            Wg[tid] = ((const float4*)W_gcn)[tid];
        }
        __syncthreads();
        int lane = tid & 15;
        long long gid = (long long)blockIdx.x * blockDim.x + tid;
        int i = (int)(gid >> 4);
        if (i >= N) return;
        float4 v = ((const float4*)(x + (size_t)i * 64))[lane];
        float4 wa = Wa[lane], wb = Wb[lane], wg = Wg[lane];
        float p1 = v.x*wa.x + v.y*wa.y + v.z*wa.z + v.w*wa.w;
        float p2 = v.x*wb.x + v.y*wb.y + v.z*wb.z + v.w*wb.w;
        float p3 = v.x*wg.x + v.y*wg.y + v.z*wg.z + v.w*wg.w;
#pragma unroll
        for (int s = 1; s < 16; s <<= 1) {
            p1 += __shfl_xor(p1, s);
            p2 += __shfl_xor(p2, s);
            p3 += __shfl_xor(p3, s);
        }
        if (lane == 0) nd[i] = make_float4(p1, p2, p3, 0.f);
    } else {
        int b = (int)blockIdx.x - nodeBlocks;
        int t = b * blockDim.x + threadIdx.x;
        int e0 = t * 4;
        if (e0 + 3 < E) {
            int4 c = *(const int4*)(colv + e0);
            atomicAdd(&dacc[c.x], 1.0f);
            atomicAdd(&dacc[c.y], 1.0f);
            atomicAdd(&dacc[c.z], 1.0f);
            atomicAdd(&dacc[c.w], 1.0f);
        } else if (e0 < E) {
            for (int e = e0; e < E; ++e) atomicAdd(&dacc[colv[e]], 1.0f);
        }
    }
}

// scalar fallback (only if E % 4 != 0)
__global__ void k_deg_s(const int* __restrict__ colv, float* __restrict__ dacc, int E) {
    int i = blockIdx.x * blockDim.x + threadIdx.x;
    if (i < E) atomicAdd(&dacc[colv[i]], 1.0f);
}

__global__ void k_dinv(float4* __restrict__ nd, float* __restrict__ dacc, int N) {
    int i = blockIdx.x * blockDim.x + threadIdx.x;
    if (i < N) {
        float4 d = nd[i];
        float dv = rsqrtf(dacc[i] + 1.0f);   // +1 self-loop
        float g = dv * d.z;                  // dinv * h
        nd[i] = make_float4(d.x, d.y, g, dv);
        dacc[i] = dv * g;                    // self-loop contribution dinv^2*h
    }
}

__global__ void k_edge(const int* __restrict__ ei, const float4* __restrict__ nd,
                       const float* __restrict__ b_edge, float* __restrict__ dacc,
                       float* __restrict__ om, float* __restrict__ os, int E) {
    int t = blockIdx.x * blockDim.x + threadIdx.x;
    int e0 = t * 4;
    float b = b_edge[0];
    if (e0 + 3 < E) {
        int4 r = *(const int4*)(ei + e0);
        int4 c = *(const int4*)(ei + E + e0);
        float4 nr0 = nd[r.x], nr1 = nd[r.y], nr2 = nd[r.z], nr3 = nd[r.w];
        float4 nc0 = nd[c.x], nc1 = nd[c.y], nc2 = nd[c.z], nc3 = nd[c.w];
        float4 m, s;
        m.x = 1.f / (1.f + expf(-(nr0.x + nc0.y + b)));
        m.y = 1.f / (1.f + expf(-(nr1.x + nc1.y + b)));
        m.z = 1.f / (1.f + expf(-(nr2.x + nc2.y + b)));
        m.w = 1.f / (1.f + expf(-(nr3.x + nc3.y + b)));
        s = make_float4(1.f - m.x, 1.f - m.y, 1.f - m.z, 1.f - m.w);
        *(float4*)(om + e0) = m;
        *(float4*)(os + e0) = s;
        atomicAdd(&dacc[c.x], nr0.z * nc0.w);
        atomicAdd(&dacc[c.y], nr1.z * nc1.w);
        atomicAdd(&dacc[c.z], nr2.z * nc2.w);
        atomicAdd(&dacc[c.w], nr3.z * nc3.w);
    } else if (e0 < E) {
        for (int e = e0; e < E; ++e) {
            int rr = ei[e], cc = ei[E + e];
            float4 nr = nd[rr], nc = nd[cc];
            float a = 1.f / (1.f + expf(-(nr.x + nc.y + b)));
            om[e] = a; os[e] = 1.f - a;
            atomicAdd(&dacc[cc], nr.z * nc.w);
        }
    }
}

// scalar fallback (only if E % 4 != 0 — vector loads would be misaligned)
__global__ void k_edge_s(const int* __restrict__ ei, const float4* __restrict__ nd,
                         const float* __restrict__ b_edge, float* __restrict__ dacc,
                         float* __restrict__ om, float* __restrict__ os, int E) {
    int e = blockIdx.x * blockDim.x + threadIdx.x;
    if (e < E) {
        int rr = ei[e], cc = ei[E + e];
        float4 nr = nd[rr], nc = nd[cc];
        float a = 1.f / (1.f + expf(-(nr.x + nc.y + b_edge[0])));
        om[e] = a; os[e] = 1.f - a;
        atomicAdd(&dacc[cc], nr.z * nc.w);
    }
}

// One block per graph; two chained ragged softmaxes over dacc (+b_gcn, which
// is softmax-invariant but kept for fidelity).
__global__ void k_softmax(const float* __restrict__ acc,
                          const float* __restrict__ b_gcn,
                          const int* __restrict__ split_n,
                          float* __restrict__ out_m,
                          float* __restrict__ out_s) {
    __shared__ float red[128];
    __shared__ int ired[128];
    __shared__ int sh_off;
    const int g = blockIdx.x;
    const int tid = threadIdx.x;
    const int BD = blockDim.x; // 128

    int part = 0;
    for (int j = tid; j < g; j += BD) part += split_n[j];
    ired[tid] = part;
    __syncthreads();
    for (int s = 64; s > 0; s >>= 1) {
        if (tid < s) ired[tid] += ired[tid + s];
        __syncthreads();
    }
    if (tid == 0) sh_off = ired[0];
    __syncthreads();
    const int off = sh_off;
    const int cnt = split_n[g];
    const float b = b_gcn[0];

    float mx = -INFINITY;
    for (int j = tid; j < cnt; j += BD) mx = fmaxf(mx, acc[off + j] + b);
    red[tid] = mx; __syncthreads();
    for (int s = 64; s > 0; s >>= 1) {
        if (tid < s) red[tid] = fmaxf(red[tid], red[tid + s]);
        __syncthreads();
    }
    mx = red[0]; __syncthreads();
    float sum = 0.f;
    for (int j = tid; j < cnt; j += BD) sum += expf(acc[off + j] + b - mx);
    red[tid] = sum; __syncthreads();
    for (int s = 64; s > 0; s >>= 1) {
        if (tid < s) red[tid] += red[tid + s];
        __syncthreads();
    }
    const float inv1 = 1.0f / red[0]; __syncthreads();
    for (int j = tid; j < cnt; j += BD)
        out_m[off + j] = expf(acc[off + j] + b - mx) * inv1;
    __syncthreads();

    float mx2 = -INFINITY;
    for (int j = tid; j < cnt; j += BD) mx2 = fmaxf(mx2, 1.0f - out_m[off + j]);
    red[tid] = mx2; __syncthreads();
    for (int s = 64; s > 0; s >>= 1) {
        if (tid < s) red[tid] = fmaxf(red[tid], red[tid + s]);
        __syncthreads();
    }
    mx2 = red[0]; __syncthreads();
    float sum2 = 0.f;
    for (int j = tid; j < cnt; j += BD) sum2 += expf(1.0f - out_m[off + j] - mx2);
    red[tid] = sum2; __syncthreads();
    for (int s = 64; s > 0; s >>= 1) {
        if (tid < s) red[tid] += red[tid + s];
        __syncthreads();
    }
    const float inv2 = 1.0f / red[0]; __syncthreads();
    for (int j = tid; j < cnt; j += BD)
        out_s[off + j] = expf(1.0f - out_m[off + j] - mx2) * inv2;
}

extern "C" void kernel_launch(void* const* d_in, const int* in_sizes, int n_in,
                              void* d_out, int out_size, void* d_ws, size_t ws_size,
                              hipStream_t stream) {
    const float* x      = (const float*)d_in[0];
    const int*   ei     = (const int*)d_in[1];
    const int*   splitn = (const int*)d_in[2];
    const float* b_edge = (const float*)d_in[4];
    const float* W_edge = (const float*)d_in[3];
    const float* W_gcn  = (const float*)d_in[5];
    const float* b_gcn  = (const float*)d_in[6];

    const int N = in_sizes[0] / 64;
    const int E = in_sizes[1] / 2;
    const int G = in_sizes[2];

    float* out = (float*)d_out;
    float* edge_m = out;
    float* edge_s = out + E;
    float* node_m = out + 2LL * E;
    float* node_s = out + 2LL * E + N;

    float4* nd   = (float4*)d_ws;
    float*  dacc = (float*)d_ws + 4LL * N;

    hipMemsetAsync(dacc, 0, (size_t)N * sizeof(float), stream);

    const bool vec = (E % 4) == 0;
    const int nodeBlocks = (N * 16 + 255) / 256;
    const int degBlocks  = vec ? (E / 4 + 255) / 256 : 0;
    k_node_deg<<<nodeBlocks + degBlocks, 256, 0, stream>>>(
        x, W_edge, W_gcn, ei + E, nd, dacc, N, E, nodeBlocks);
    if (!vec)
        k_deg_s<<<(E + 255) / 256, 256, 0, stream>>>(ei + E, dacc, E);

    k_dinv<<<(N + 255) / 256, 256, 0, stream>>>(nd, dacc, N);

    if (vec)
        k_edge<<<(E / 4 + 255) / 256, 256, 0, stream>>>(
            ei, nd, b_edge, dacc, edge_m, edge_s, E);
    else
        k_edge_s<<<(E + 255) / 256, 256, 0, stream>>>(
            ei, nd, b_edge, dacc, edge_m, edge_s, E);

    k_softmax<<<G, 128, 0, stream>>>(dacc, b_gcn, splitn, node_m, node_s);
}

// Round 3
// 116.554 us; speedup vs baseline: 1.0923x; 1.0204x over previous
//
#include <hip/hip_runtime.h>
#include <math.h>

// ---------------------------------------------------------------------------
// Att_cov. Round-3 structure: separable edge linear -> per-node scalars.
//   ed2[i] = (pa, pb) = (x_i·Wa, x_i·Wb)         [gathered by edge-att pass]
//   gd2[i] = (g, dinv) = (dinv_i*h_i, dinv_i)    [gathered by acc pass]
// Atomic passes (deg histogram, acc scatter) use NC=8 shadow copies to cut
// per-cacheline serialization at the device-coherence point 8x.
// ws layout (floats): ed2[2N] | gd2[2N] | S[NC*N]
// ---------------------------------------------------------------------------

#define SOFT_LDS_CAP 2048

__global__ void k_node(const float* __restrict__ x,
                       const float* __restrict__ W_edge,
                       const float* __restrict__ W_gcn,
                       float2* __restrict__ ed2,
                       float2* __restrict__ gd2,
                       int N) {
    __shared__ float4 Wa[16], Wb[16], Wg[16];
    int tid = threadIdx.x;
    if (tid < 16) {
        Wa[tid] = ((const float4*)W_edge)[tid];
        Wb[tid] = ((const float4*)W_edge)[16 + tid];
        Wg[tid] = ((const float4*)W_gcn)[tid];
    }
    __syncthreads();
    int lane = tid & 15;
    long long gid = (long long)blockIdx.x * blockDim.x + tid;
    int i = (int)(gid >> 4);
    if (i >= N) return;
    float4 v = ((const float4*)(x + (size_t)i * 64))[lane];
    float4 wa = Wa[lane], wb = Wb[lane], wg = Wg[lane];
    float p1 = v.x*wa.x + v.y*wa.y + v.z*wa.z + v.w*wa.w;
    float p2 = v.x*wb.x + v.y*wb.y + v.z*wb.z + v.w*wb.w;
    float p3 = v.x*wg.x + v.y*wg.y + v.z*wg.z + v.w*wg.w;
#pragma unroll
    for (int s = 1; s < 16; s <<= 1) {
        p1 += __shfl_xor(p1, s);
        p2 += __shfl_xor(p2, s);
        p3 += __shfl_xor(p3, s);
    }
    if (lane == 0) {
        ed2[i] = make_float2(p1, p2);
        gd2[i] = make_float2(p3, 0.f);   // h; dinv filled by k_dinv
    }
}

// Edge attention sigmoid + degree histogram (shadow atomics), 4 edges/thread.
__global__ void k_att_deg(const int* __restrict__ ei,
                          const float2* __restrict__ ed2,
                          const float* __restrict__ b_edge,
                          float* __restrict__ S, int N, int E, int NC,
                          float* __restrict__ om, float* __restrict__ os) {
    int t = blockIdx.x * blockDim.x + threadIdx.x;
    int e0 = t * 4;
    const float b = b_edge[0];
    float* Sc = S + (size_t)(((blockIdx.x << 2) | (threadIdx.x >> 6)) & (NC - 1)) * N;
    if (e0 + 3 < E) {
        int4 r = *(const int4*)(ei + e0);
        int4 c = *(const int4*)(ei + E + e0);
        float2 a0 = ed2[r.x], a1 = ed2[r.y], a2 = ed2[r.z], a3 = ed2[r.w];
        float2 b0 = ed2[c.x], b1 = ed2[c.y], b2 = ed2[c.z], b3 = ed2[c.w];
        float4 m;
        m.x = 1.f / (1.f + expf(-(a0.x + b0.y + b)));
        m.y = 1.f / (1.f + expf(-(a1.x + b1.y + b)));
        m.z = 1.f / (1.f + expf(-(a2.x + b2.y + b)));
        m.w = 1.f / (1.f + expf(-(a3.x + b3.y + b)));
        *(float4*)(om + e0) = m;
        *(float4*)(os + e0) = make_float4(1.f - m.x, 1.f - m.y, 1.f - m.z, 1.f - m.w);
        atomicAdd(&Sc[c.x], 1.0f);
        atomicAdd(&Sc[c.y], 1.0f);
        atomicAdd(&Sc[c.z], 1.0f);
        atomicAdd(&Sc[c.w], 1.0f);
    } else if (e0 < E) {
        for (int e = e0; e < E; ++e) {
            int rr = ei[e], cc = ei[E + e];
            float a = 1.f / (1.f + expf(-(ed2[rr].x + ed2[cc].y + b)));
            om[e] = a; os[e] = 1.f - a;
            atomicAdd(&Sc[cc], 1.0f);
        }
    }
}

__global__ void k_dinv(float2* __restrict__ gd2, float* __restrict__ S, int N, int NC) {
    int i = blockIdx.x * blockDim.x + threadIdx.x;
    if (i >= N) return;
    float deg = 1.0f;   // self-loop
    for (int c = 0; c < NC; ++c) deg += S[(size_t)c * N + i];
    float h = gd2[i].x;
    float dv = rsqrtf(deg);
    float g = dv * h;
    gd2[i] = make_float2(g, dv);
    S[i] = dv * g;      // self-loop contribution dinv^2 * h, seeds copy 0
    for (int c = 1; c < NC; ++c) S[(size_t)c * N + i] = 0.f;
}

// GCN scatter: acc[col] += g[row] * dinv[col], shadow atomics, 4 edges/thread.
__global__ void k_acc(const int* __restrict__ ei,
                      const float2* __restrict__ gd2,
                      float* __restrict__ S, int N, int E, int NC) {
    int t = blockIdx.x * blockDim.x + threadIdx.x;
    int e0 = t * 4;
    float* Sc = S + (size_t)(((blockIdx.x << 2) | (threadIdx.x >> 6)) & (NC - 1)) * N;
    if (e0 + 3 < E) {
        int4 r = *(const int4*)(ei + e0);
        int4 c = *(const int4*)(ei + E + e0);
        float2 r0 = gd2[r.x], r1 = gd2[r.y], r2 = gd2[r.z], r3 = gd2[r.w];
        float2 c0 = gd2[c.x], c1 = gd2[c.y], c2 = gd2[c.z], c3 = gd2[c.w];
        atomicAdd(&Sc[c.x], r0.x * c0.y);
        atomicAdd(&Sc[c.y], r1.x * c1.y);
        atomicAdd(&Sc[c.z], r2.x * c2.y);
        atomicAdd(&Sc[c.w], r3.x * c3.y);
    } else if (e0 < E) {
        for (int e = e0; e < E; ++e) {
            int rr = ei[e], cc = ei[E + e];
            atomicAdd(&Sc[cc], gd2[rr].x * gd2[cc].y);
        }
    }
}

// One block per graph: sum NC shadow copies (fused reduce), then two chained
// ragged softmaxes. b_gcn omitted: softmax is shift-invariant.
__global__ void k_softmax(const float* __restrict__ S, int N, int NC,
                          const int* __restrict__ split_n,
                          float* __restrict__ out_m, float* __restrict__ out_s) {
    __shared__ float red[128];
    __shared__ int ired[128];
    __shared__ int sh_off;
    __shared__ float sv[SOFT_LDS_CAP];
    const int g = blockIdx.x;
    const int tid = threadIdx.x;
    const int BD = blockDim.x;

    int part = 0;
    for (int j = tid; j < g; j += BD) part += split_n[j];
    ired[tid] = part;
    __syncthreads();
    for (int s = 64; s > 0; s >>= 1) {
        if (tid < s) ired[tid] += ired[tid + s];
        __syncthreads();
    }
    if (tid == 0) sh_off = ired[0];
    __syncthreads();
    const int off = sh_off;
    const int cnt = split_n[g];

    if (cnt <= SOFT_LDS_CAP) {
        for (int j = tid; j < cnt; j += BD) {
            float v = 0.f;
            for (int c = 0; c < NC; ++c) v += S[(size_t)c * N + off + j];
            sv[j] = v;
        }
        __syncthreads();
        // softmax #1
        float mx = -INFINITY;
        for (int j = tid; j < cnt; j += BD) mx = fmaxf(mx, sv[j]);
        red[tid] = mx; __syncthreads();
        for (int s = 64; s > 0; s >>= 1) {
            if (tid < s) red[tid] = fmaxf(red[tid], red[tid + s]);
            __syncthreads();
        }
        mx = red[0]; __syncthreads();
        float sum = 0.f;
        for (int j = tid; j < cnt; j += BD) sum += expf(sv[j] - mx);
        red[tid] = sum; __syncthreads();
        for (int s = 64; s > 0; s >>= 1) {
            if (tid < s) red[tid] += red[tid + s];
            __syncthreads();
        }
        const float inv1 = 1.0f / red[0]; __syncthreads();
        for (int j = tid; j < cnt; j += BD) {
            float mval = expf(sv[j] - mx) * inv1;
            out_m[off + j] = mval;
            sv[j] = mval;            // own index: no cross-thread hazard
        }
        __syncthreads();
        // softmax #2 over (1 - m)
        float mx2 = -INFINITY;
        for (int j = tid; j < cnt; j += BD) mx2 = fmaxf(mx2, 1.0f - sv[j]);
        red[tid] = mx2; __syncthreads();
        for (int s = 64; s > 0; s >>= 1) {
            if (tid < s) red[tid] = fmaxf(red[tid], red[tid + s]);
            __syncthreads();
        }
        mx2 = red[0]; __syncthreads();
        float sum2 = 0.f;
        for (int j = tid; j < cnt; j += BD) sum2 += expf(1.0f - sv[j] - mx2);
        red[tid] = sum2; __syncthreads();
        for (int s = 64; s > 0; s >>= 1) {
            if (tid < s) red[tid] += red[tid + s];
            __syncthreads();
        }
        const float inv2 = 1.0f / red[0]; __syncthreads();
        for (int j = tid; j < cnt; j += BD)
            out_s[off + j] = expf(1.0f - sv[j] - mx2) * inv2;
    } else {
        // generic fallback: recompute shadow sum on each read
        float mx = -INFINITY;
        for (int j = tid; j < cnt; j += BD) {
            float v = 0.f;
            for (int c = 0; c < NC; ++c) v += S[(size_t)c * N + off + j];
            mx = fmaxf(mx, v);
        }
        red[tid] = mx; __syncthreads();
        for (int s = 64; s > 0; s >>= 1) {
            if (tid < s) red[tid] = fmaxf(red[tid], red[tid + s]);
            __syncthreads();
        }
        mx = red[0]; __syncthreads();
        float sum = 0.f;
        for (int j = tid; j < cnt; j += BD) {
            float v = 0.f;
            for (int c = 0; c < NC; ++c) v += S[(size_t)c * N + off + j];
            sum += expf(v - mx);
        }
        red[tid] = sum; __syncthreads();
        for (int s = 64; s > 0; s >>= 1) {
            if (tid < s) red[tid] += red[tid + s];
            __syncthreads();
        }
        const float inv1 = 1.0f / red[0]; __syncthreads();
        for (int j = tid; j < cnt; j += BD) {
            float v = 0.f;
            for (int c = 0; c < NC; ++c) v += S[(size_t)c * N + off + j];
            out_m[off + j] = expf(v - mx) * inv1;
        }
        __syncthreads();
        float mx2 = -INFINITY;
        for (int j = tid; j < cnt; j += BD) mx2 = fmaxf(mx2, 1.0f - out_m[off + j]);
        red[tid] = mx2; __syncthreads();
        for (int s = 64; s > 0; s >>= 1) {
            if (tid < s) red[tid] = fmaxf(red[tid], red[tid + s]);
            __syncthreads();
        }
        mx2 = red[0]; __syncthreads();
        float sum2 = 0.f;
        for (int j = tid; j < cnt; j += BD) sum2 += expf(1.0f - out_m[off + j] - mx2);
        red[tid] = sum2; __syncthreads();
        for (int s = 64; s > 0; s >>= 1) {
            if (tid < s) red[tid] += red[tid + s];
            __syncthreads();
        }
        const float inv2 = 1.0f / red[0]; __syncthreads();
        for (int j = tid; j < cnt; j += BD)
            out_s[off + j] = expf(1.0f - out_m[off + j] - mx2) * inv2;
    }
}

extern "C" void kernel_launch(void* const* d_in, const int* in_sizes, int n_in,
                              void* d_out, int out_size, void* d_ws, size_t ws_size,
                              hipStream_t stream) {
    const float* x      = (const float*)d_in[0];
    const int*   ei     = (const int*)d_in[1];
    const int*   splitn = (const int*)d_in[2];
    const float* W_edge = (const float*)d_in[3];
    const float* b_edge = (const float*)d_in[4];
    const float* W_gcn  = (const float*)d_in[5];

    const int N = in_sizes[0] / 64;
    const int E = in_sizes[1] / 2;
    const int G = in_sizes[2];

    float* out = (float*)d_out;
    float* edge_m = out;
    float* edge_s = out + E;
    float* node_m = out + 2LL * E;
    float* node_s = out + 2LL * E + N;

    // pick largest power-of-2 shadow count that fits: (4 + NC) * N floats
    int NC = 8;
    while (NC > 1 && (size_t)(4 + NC) * N * sizeof(float) > ws_size) NC >>= 1;

    float2* ed2 = (float2*)d_ws;
    float2* gd2 = ed2 + N;
    float*  S   = (float*)d_ws + 4LL * N;

    hipMemsetAsync(S, 0, (size_t)NC * N * sizeof(float), stream);

    k_node<<<(N * 16 + 255) / 256, 256, 0, stream>>>(x, W_edge, W_gcn, ed2, gd2, N);

    const int edgeThreads = (E + 3) / 4;
    const int edgeBlocks = (edgeThreads + 255) / 256;
    k_att_deg<<<edgeBlocks, 256, 0, stream>>>(ei, ed2, b_edge, S, N, E, NC,
                                              edge_m, edge_s);
    k_dinv<<<(N + 255) / 256, 256, 0, stream>>>(gd2, S, N, NC);
    k_acc<<<edgeBlocks, 256, 0, stream>>>(ei, gd2, S, N, E, NC);
    k_softmax<<<G, 128, 0, stream>>>(S, N, NC, splitn, node_m, node_s);
}

// Round 4
// 88.401 us; speedup vs baseline: 1.4402x; 1.3185x over previous
//
#include <hip/hip_runtime.h>
#include <math.h>

// ---------------------------------------------------------------------------
// Att_cov, round 4: NO global atomics.
// Separable edge linear -> per-node scalars (ed2 = (pa,pb), h).
// deg histogram and GCN scatter are done as partitioned scatter->gather:
//   nodes split into R ranges of RANGE=2048 (8KB LDS table),
//   edges split into C chunks; block (r,c) scans chunk c's col stream
//   (L2-resident), bins in-range hits with LDS atomics, writes its table
//   slice to partial[c][range] with plain coalesced stores.
// Reduce kernels sum the C partials per node (coalesced).
// ws layout (floats): ed2[2N] | hbuf[N] (h->g) | dv1[N] | acc[N] | partial[C*N]
// ---------------------------------------------------------------------------

#define RANGE 2048
#define SOFT_LDS_CAP 2048

__global__ void k_node(const float* __restrict__ x,
                       const float* __restrict__ W_edge,
                       const float* __restrict__ W_gcn,
                       float2* __restrict__ ed2,
                       float* __restrict__ hbuf,
                       int N) {
    __shared__ float4 Wa[16], Wb[16], Wg[16];
    int tid = threadIdx.x;
    if (tid < 16) {
        Wa[tid] = ((const float4*)W_edge)[tid];
        Wb[tid] = ((const float4*)W_edge)[16 + tid];
        Wg[tid] = ((const float4*)W_gcn)[tid];
    }
    __syncthreads();
    int lane = tid & 15;
    long long gid = (long long)blockIdx.x * blockDim.x + tid;
    int i = (int)(gid >> 4);
    if (i >= N) return;
    float4 v = ((const float4*)(x + (size_t)i * 64))[lane];
    float4 wa = Wa[lane], wb = Wb[lane], wg = Wg[lane];
    float p1 = v.x*wa.x + v.y*wa.y + v.z*wa.z + v.w*wa.w;
    float p2 = v.x*wb.x + v.y*wb.y + v.z*wb.z + v.w*wb.w;
    float p3 = v.x*wg.x + v.y*wg.y + v.z*wg.z + v.w*wg.w;
#pragma unroll
    for (int s = 1; s < 16; s <<= 1) {
        p1 += __shfl_xor(p1, s);
        p2 += __shfl_xor(p2, s);
        p3 += __shfl_xor(p3, s);
    }
    if (lane == 0) {
        ed2[i] = make_float2(p1, p2);
        hbuf[i] = p3;
    }
}

// Fused: blocks [0, attBlocks) compute edge attention (pure gather+store);
// blocks [attBlocks, attBlocks+R*C) build the partitioned degree histogram.
__global__ void k_att_hist(const int* __restrict__ ei,
                           const float2* __restrict__ ed2,
                           const float* __restrict__ b_edge,
                           float* __restrict__ om, float* __restrict__ os,
                           float* __restrict__ partial,
                           int N, int E, int CH, int R, int attBlocks, int vec) {
    __shared__ float table[RANGE];
    const int bid = blockIdx.x;
    if (bid < attBlocks) {
        int t = bid * blockDim.x + threadIdx.x;
        int e0 = t * 4;
        const float b = b_edge[0];
        if (vec && e0 + 3 < E) {
            int4 r = *(const int4*)(ei + e0);
            int4 c = *(const int4*)(ei + E + e0);
            float4 m;
            m.x = 1.f / (1.f + expf(-(ed2[r.x].x + ed2[c.x].y + b)));
            m.y = 1.f / (1.f + expf(-(ed2[r.y].x + ed2[c.y].y + b)));
            m.z = 1.f / (1.f + expf(-(ed2[r.z].x + ed2[c.z].y + b)));
            m.w = 1.f / (1.f + expf(-(ed2[r.w].x + ed2[c.w].y + b)));
            *(float4*)(om + e0) = m;
            *(float4*)(os + e0) = make_float4(1.f - m.x, 1.f - m.y, 1.f - m.z, 1.f - m.w);
        } else if (e0 < E) {
            int ee = (E < e0 + 4) ? E : e0 + 4;
            for (int e = e0; e < ee; ++e) {
                float a = 1.f / (1.f + expf(-(ed2[ei[e]].x + ed2[ei[E + e]].y + b)));
                om[e] = a; os[e] = 1.f - a;
            }
        }
        return;
    }
    const int hb = bid - attBlocks;
    const int c = hb / R;
    const int r = hb - c * R;
    const int lo = r * RANGE;
    for (int j = threadIdx.x; j < RANGE; j += blockDim.x) table[j] = 0.f;
    __syncthreads();
    const int e_lo = c * CH;
    const int e_hi = (E < e_lo + CH) ? E : (e_lo + CH);
    const int* __restrict__ col = ei + E;
    for (int e = e_lo + (int)threadIdx.x * 4; e < e_hi; e += blockDim.x * 4) {
        if (vec && e + 3 < e_hi) {
            int4 cc = *(const int4*)(col + e);
            unsigned u;
            u = (unsigned)(cc.x - lo); if (u < RANGE) atomicAdd(&table[u], 1.f);
            u = (unsigned)(cc.y - lo); if (u < RANGE) atomicAdd(&table[u], 1.f);
            u = (unsigned)(cc.z - lo); if (u < RANGE) atomicAdd(&table[u], 1.f);
            u = (unsigned)(cc.w - lo); if (u < RANGE) atomicAdd(&table[u], 1.f);
        } else {
            int ee = (e_hi < e + 4) ? e_hi : e + 4;
            for (int q = e; q < ee; ++q) {
                unsigned u = (unsigned)(col[q] - lo);
                if (u < RANGE) atomicAdd(&table[u], 1.f);
            }
        }
    }
    __syncthreads();
    const size_t base = (size_t)c * N;
    for (int j = threadIdx.x; j < RANGE; j += blockDim.x) {
        int node = lo + j;
        if (node < N) partial[base + node] = table[j];
    }
}

// deg -> dinv; g = h*dinv; acc seeded with self-loop dinv^2*h.
__global__ void k_dinv(const float* __restrict__ partial,
                       float* __restrict__ hbuf,   // in: h, out: g
                       float* __restrict__ dv1,
                       float* __restrict__ acc,
                       int N, int C) {
    int i = blockIdx.x * blockDim.x + threadIdx.x;
    if (i >= N) return;
    float deg = 1.0f;  // self-loop
    for (int c = 0; c < C; ++c) deg += partial[(size_t)c * N + i];
    float h = hbuf[i];
    float dv = rsqrtf(deg);
    hbuf[i] = h * dv;
    dv1[i] = dv;
    acc[i] = dv * dv * h;
}

// Partitioned GCN scatter: table[col-lo] += g[row].
__global__ void k_scat(const int* __restrict__ ei,
                       const float* __restrict__ g1,
                       float* __restrict__ partial,
                       int N, int E, int CH, int R, int vec) {
    __shared__ float table[RANGE];
    const int c = blockIdx.x / R;
    const int r = blockIdx.x - c * R;
    const int lo = r * RANGE;
    for (int j = threadIdx.x; j < RANGE; j += blockDim.x) table[j] = 0.f;
    __syncthreads();
    const int e_lo = c * CH;
    const int e_hi = (E < e_lo + CH) ? E : (e_lo + CH);
    const int* __restrict__ row = ei;
    const int* __restrict__ col = ei + E;
    for (int e = e_lo + (int)threadIdx.x * 4; e < e_hi; e += blockDim.x * 4) {
        if (vec && e + 3 < e_hi) {
            int4 rr = *(const int4*)(row + e);
            int4 cc = *(const int4*)(col + e);
            unsigned u;
            u = (unsigned)(cc.x - lo); if (u < RANGE) atomicAdd(&table[u], g1[rr.x]);
            u = (unsigned)(cc.y - lo); if (u < RANGE) atomicAdd(&table[u], g1[rr.y]);
            u = (unsigned)(cc.z - lo); if (u < RANGE) atomicAdd(&table[u], g1[rr.z]);
            u = (unsigned)(cc.w - lo); if (u < RANGE) atomicAdd(&table[u], g1[rr.w]);
        } else {
            int ee = (e_hi < e + 4) ? e_hi : e + 4;
            for (int q = e; q < ee; ++q) {
                unsigned u = (unsigned)(col[q] - lo);
                if (u < RANGE) atomicAdd(&table[u], g1[row[q]]);
            }
        }
    }
    __syncthreads();
    const size_t base = (size_t)c * N;
    for (int j = threadIdx.x; j < RANGE; j += blockDim.x) {
        int node = lo + j;
        if (node < N) partial[base + node] = table[j];
    }
}

__global__ void k_red(const float* __restrict__ partial,
                      const float* __restrict__ dv1,
                      float* __restrict__ acc,
                      int N, int C) {
    int i = blockIdx.x * blockDim.x + threadIdx.x;
    if (i >= N) return;
    float s = 0.f;
    for (int c = 0; c < C; ++c) s += partial[(size_t)c * N + i];
    acc[i] += dv1[i] * s;
}

// One block per graph; two chained ragged softmaxes over acc.
// (b_gcn omitted: softmax is shift-invariant.)
__global__ void k_softmax(const float* __restrict__ acc,
                          const int* __restrict__ split_n,
                          float* __restrict__ out_m, float* __restrict__ out_s) {
    __shared__ float red[128];
    __shared__ int ired[128];
    __shared__ int sh_off;
    __shared__ float sv[SOFT_LDS_CAP];
    const int g = blockIdx.x;
    const int tid = threadIdx.x;
    const int BD = blockDim.x;

    int part = 0;
    for (int j = tid; j < g; j += BD) part += split_n[j];
    ired[tid] = part;
    __syncthreads();
    for (int s = 64; s > 0; s >>= 1) {
        if (tid < s) ired[tid] += ired[tid + s];
        __syncthreads();
    }
    if (tid == 0) sh_off = ired[0];
    __syncthreads();
    const int off = sh_off;
    const int cnt = split_n[g];
    const bool fits = (cnt <= SOFT_LDS_CAP);

    if (fits) {
        for (int j = tid; j < cnt; j += BD) sv[j] = acc[off + j];
        __syncthreads();
    }
    // softmax #1
    float mx = -INFINITY;
    for (int j = tid; j < cnt; j += BD) mx = fmaxf(mx, fits ? sv[j] : acc[off + j]);
    red[tid] = mx; __syncthreads();
    for (int s = 64; s > 0; s >>= 1) {
        if (tid < s) red[tid] = fmaxf(red[tid], red[tid + s]);
        __syncthreads();
    }
    mx = red[0]; __syncthreads();
    float sum = 0.f;
    for (int j = tid; j < cnt; j += BD) sum += expf((fits ? sv[j] : acc[off + j]) - mx);
    red[tid] = sum; __syncthreads();
    for (int s = 64; s > 0; s >>= 1) {
        if (tid < s) red[tid] += red[tid + s];
        __syncthreads();
    }
    const float inv1 = 1.0f / red[0]; __syncthreads();
    for (int j = tid; j < cnt; j += BD) {
        float mval = expf((fits ? sv[j] : acc[off + j]) - mx) * inv1;
        out_m[off + j] = mval;
        if (fits) sv[j] = mval;
    }
    __syncthreads();
    // softmax #2 over (1 - m)
    float mx2 = -INFINITY;
    for (int j = tid; j < cnt; j += BD)
        mx2 = fmaxf(mx2, 1.0f - (fits ? sv[j] : out_m[off + j]));
    red[tid] = mx2; __syncthreads();
    for (int s = 64; s > 0; s >>= 1) {
        if (tid < s) red[tid] = fmaxf(red[tid], red[tid + s]);
        __syncthreads();
    }
    mx2 = red[0]; __syncthreads();
    float sum2 = 0.f;
    for (int j = tid; j < cnt; j += BD)
        sum2 += expf(1.0f - (fits ? sv[j] : out_m[off + j]) - mx2);
    red[tid] = sum2; __syncthreads();
    for (int s = 64; s > 0; s >>= 1) {
        if (tid < s) red[tid] += red[tid + s];
        __syncthreads();
    }
    const float inv2 = 1.0f / red[0]; __syncthreads();
    for (int j = tid; j < cnt; j += BD)
        out_s[off + j] = expf(1.0f - (fits ? sv[j] : out_m[off + j]) - mx2) * inv2;
}

extern "C" void kernel_launch(void* const* d_in, const int* in_sizes, int n_in,
                              void* d_out, int out_size, void* d_ws, size_t ws_size,
                              hipStream_t stream) {
    const float* x      = (const float*)d_in[0];
    const int*   ei     = (const int*)d_in[1];
    const int*   splitn = (const int*)d_in[2];
    const float* W_edge = (const float*)d_in[3];
    const float* b_edge = (const float*)d_in[4];
    const float* W_gcn  = (const float*)d_in[5];

    const int N = in_sizes[0] / 64;
    const int E = in_sizes[1] / 2;
    const int G = in_sizes[2];

    float* out = (float*)d_out;
    float* edge_m = out;
    float* edge_s = out + E;
    float* node_m = out + 2LL * E;
    float* node_s = out + 2LL * E + N;

    // chunk count: fit (5 + C) * N floats in ws
    int C = 32;
    while (C > 2 && (size_t)(5 + C) * N * sizeof(float) > ws_size) C >>= 1;
    const int R  = (N + RANGE - 1) / RANGE;
    const int CH = (((E + C - 1) / C) + 3) & ~3;
    const int vec = ((E & 3) == 0) ? 1 : 0;

    float2* ed2    = (float2*)d_ws;
    float*  hbuf   = (float*)d_ws + 2LL * N;   // h, then g = h*dinv
    float*  dv1    = hbuf + N;
    float*  acc    = dv1 + N;
    float*  partial = acc + N;

    const int attBlocks = ((E + 3) / 4 + 255) / 256;

    k_node<<<(N * 16 + 255) / 256, 256, 0, stream>>>(x, W_edge, W_gcn, ed2, hbuf, N);
    k_att_hist<<<attBlocks + R * C, 256, 0, stream>>>(
        ei, ed2, b_edge, edge_m, edge_s, partial, N, E, CH, R, attBlocks, vec);
    k_dinv<<<(N + 255) / 256, 256, 0, stream>>>(partial, hbuf, dv1, acc, N, C);
    k_scat<<<R * C, 256, 0, stream>>>(ei, hbuf, partial, N, E, CH, R, vec);
    k_red<<<(N + 255) / 256, 256, 0, stream>>>(partial, dv1, acc, N, C);
    k_softmax<<<G, 128, 0, stream>>>(acc, splitn, node_m, node_s);
}